// Round 19
// baseline (123.098 us; speedup 1.0000x reference)
//
#include <hip/hip_runtime.h>
#include <math.h>

typedef short bf16x8 __attribute__((ext_vector_type(8)));
typedef float f32x4  __attribute__((ext_vector_type(4)));

#define N_SMPS 16384
#define N_FCNS 2048
#define D_IN 32
#define D_OUT 32
#define KNN 4
#define SPLITS 4
#define CPS 512            // centers per split (one wave per split)
#define TILES 32           // CPS / 16
#define POOL 48            // 8 subsets x top-6, all-distinct candidates
#define SMP 8              // samples per block (MFMA rows 8-15 are duplicates)

__device__ __forceinline__ unsigned umin_u(unsigned a, unsigned b) { return a < b ? a : b; }
__device__ __forceinline__ unsigned umax_u(unsigned a, unsigned b) { return a > b ? a : b; }

// round-to-nearest-even fp32 -> bf16
__device__ __forceinline__ unsigned short bf16_rne(float f) {
  unsigned b = __float_as_uint(f);
  unsigned r = b + 0x7FFFu + ((b >> 16) & 1u);
  return (unsigned short)(r >> 16);
}

// ---------------- ws layout (bytes) ------------------------------------------
// xh 1MB | ch 128K | hb 8K | wb 4MB   -> ~5.2 MB
#define OFF_XH   0u
#define OFF_CH   1048576u
#define OFF_HB   (OFF_CH + 131072u)
#define OFF_WB   (OFF_HB + 8192u)

#define NX4 (N_SMPS * D_IN / 4)            // 131072
#define NC4 (N_FCNS * D_IN / 4)            // 16384
#define NW4 (N_FCNS * D_IN * D_OUT / 4)    // 524288
#define NTOT (NX4 + NC4 + NW4)             // 671744 = 2624 * 256

// ---------------- Kernel 0: bf16 RNE conversion (x, ctrs, W) + norms ---------
// (byte-identical to R16's passing k_prep)
__global__ __launch_bounds__(256) void k_prep(
    const float* __restrict__ x, const float* __restrict__ ctrs,
    const float* __restrict__ wts,
    unsigned short* __restrict__ xh, unsigned short* __restrict__ ch,
    unsigned short* __restrict__ wb, float* __restrict__ hb)
{
  const int gt = blockIdx.x * 256 + threadIdx.x;
  const float* src; unsigned short* dst; int i4;
  if (gt < NX4)            { src = x;    dst = xh; i4 = gt; }
  else if (gt < NX4 + NC4) { src = ctrs; dst = ch; i4 = gt - NX4; }
  else                     { src = wts;  dst = wb; i4 = gt - (NX4 + NC4); }
  float4 v = ((const float4*)src)[i4];
  ushort4 o;
  o.x = bf16_rne(v.x); o.y = bf16_rne(v.y);
  o.z = bf16_rne(v.z); o.w = bf16_rne(v.w);
  ((ushort4*)dst)[i4] = o;

  if (gt < N_FCNS) {   // fp32-exact half-norms from original ctrs
    const float4* cp4 = (const float4*)(ctrs + (size_t)gt * D_IN);
    float a = 0.f;
    #pragma unroll
    for (int q = 0; q < 8; ++q) {
      float4 c = cp4[q];
      a += c.x * c.x + c.y * c.y + c.z * c.z + c.w * c.w;
    }
    hb[gt] = -0.5f * a;
  }
}

// ---------------- Kernel 1: MEGA (SMP=8, 2048 blocks, ~32 waves/CU) ----------
// R16 logic with half the samples per block: 2x resident waves to hide the
// latency that capped R16 at VALUBusy 38%. MFMA rows 8-15 are duplicate
// samples (A-frag col&7); their ladder results never written (quad<2 gate).
// hb via depth-4 global prefetch (R13-proven); s_hb dropped to fit 8 blocks/CU.
// Per-real-sample selection math bit-identical to R16 -> absmax 1.907e-6.
__global__ __launch_bounds__(256) void k_mega(
    const unsigned short* __restrict__ xh, const unsigned short* __restrict__ ch,
    const float* __restrict__ hb,
    const float* __restrict__ x, const float* __restrict__ ctrs,
    const unsigned short* __restrict__ wb, const float* __restrict__ offs,
    float* __restrict__ y)
{
  // arena: phase1 cand = 4*8*16*4 u32 = 8192 B;
  //        phase4/5 diff = 8*4*33 f32 = 4224 B, part = 8*4*8 f32x4 = 4096 B
  __shared__ __align__(16) char u_mem[8448];
  __shared__ unsigned s_pool[SMP][POOL];                       // 1.5 KB
  __shared__ double   s_pd2[SMP][POOL];                        // 3 KB
  __shared__ int      s_pix[SMP][POOL];                        // 1.5 KB
  __shared__ int      s_sel[SMP][KNN];                         // 128 B

  unsigned* s_cand = (unsigned*)u_mem;          // [w][row<8][col][e] flattened
  float*    s_diff = (float*)u_mem;             // [sl][j][33] flattened
  float4*   s_part = (float4*)(u_mem + 4224);   // [sl][j][8] flattened

  const int tid = threadIdx.x;
  const int lane = tid & 63;
  const int w = __builtin_amdgcn_readfirstlane(tid >> 6);  // wave = split
  const int col = lane & 15;
  const int quad = lane >> 4;
  const int sbase = blockIdx.x * SMP;
  const int nbase0 = w * CPS;

  // ---- Phase 1: MFMA topk ----
  // A rows 8-15 duplicate rows 0-7 (in-bounds, results discarded)
  const bf16x8 ah =
      *(const bf16x8*)(xh + (size_t)(sbase + (col & 7)) * D_IN + quad * 8);

  unsigned ls[4][4];
  #pragma unroll
  for (int r = 0; r < 4; ++r)
    #pragma unroll
    for (int e = 0; e < 4; ++e) ls[r][e] = 0u;   // real keys always > 0

  const unsigned short* chb =
      ch + (size_t)nbase0 * D_IN + (size_t)col * D_IN + quad * 8;
  #define BLOAD(t) (*(const bf16x8*)(chb + (size_t)(t) * 16 * D_IN))
  #define HLOAD(t) (hb[nbase0 + (t) * 16 + col])

  bf16x8 bh[4];
  float  hv[4];
  #pragma unroll
  for (int p = 0; p < 4; ++p) { bh[p] = BLOAD(p); hv[p] = HLOAD(p); }

  for (int t = 0; t < TILES; t += 4) {
    #pragma unroll
    for (int p = 0; p < 4; ++p) {
      {
        f32x4 acc = {0.f, 0.f, 0.f, 0.f};
        acc = __builtin_amdgcn_mfma_f32_16x16x32_bf16(ah, bh[p], acc, 0, 0, 0);
        const unsigned tc = (unsigned)((t + p) * 16 + col);
        const float hvv = hv[p];
        #pragma unroll
        for (int r = 0; r < 4; ++r) {
          const float uu = acc[r] + hvv;
          unsigned b = __float_as_uint(uu);
          unsigned m = b ^ ((unsigned)((int)b >> 31) | 0x80000000u);
          unsigned key = (m & 0xFFFFFE00u) | tc;
          unsigned t0 = umin_u(ls[r][0], key); ls[r][0] = umax_u(ls[r][0], key);
          unsigned t1 = umin_u(ls[r][1], t0);  ls[r][1] = umax_u(ls[r][1], t0);
          unsigned t2 = umin_u(ls[r][2], t1);  ls[r][2] = umax_u(ls[r][2], t1);
          ls[r][3] = umax_u(ls[r][3], t2);
        }
      }
      const int tn = (t + 4 + p) & (TILES - 1);
      bh[p] = BLOAD(tn);
      hv[p] = HLOAD(tn);
    }
  }
  #undef BLOAD
  #undef HLOAD

  // only quads 0-1 hold real sample rows (0-7)
  if (quad < 2) {
    #pragma unroll
    for (int r = 0; r < 4; ++r) {
      const int row = quad * 4 + r;
      *(uint4*)&s_cand[(((w * SMP) + row) * 16 + col) * 4] =
          make_uint4(ls[r][0], ls[r][1], ls[r][2], ls[r][3]);
    }
  }
  __syncthreads();

  // subset top-6 -> s_pool (same subset mapping: g = wave*2 + col-half)
  if (tid < SMP * 8) {
    const int sl = tid >> 3;
    const int g  = tid & 7;
    const int wv = g >> 1;
    const int chh = (g & 1) * 8;
    unsigned q0 = 0, q1 = 0, q2 = 0, q3 = 0, q4 = 0, q5 = 0;
    #pragma unroll
    for (int c2 = 0; c2 < 8; ++c2) {
      uint4 kv =
          *(const uint4*)&s_cand[(((wv * SMP) + sl) * 16 + chh + c2) * 4];
      unsigned ks[4] = {kv.x, kv.y, kv.z, kv.w};
      #pragma unroll
      for (int e = 0; e < 4; ++e) {
        unsigned key = ks[e];
        unsigned t0 = umin_u(q0, key); q0 = umax_u(q0, key);
        unsigned t1 = umin_u(q1, t0);  q1 = umax_u(q1, t0);
        unsigned t2 = umin_u(q2, t1);  q2 = umax_u(q2, t1);
        unsigned t3 = umin_u(q3, t2);  q3 = umax_u(q3, t2);
        unsigned t4 = umin_u(q4, t3);  q4 = umax_u(q4, t3);
        q5 = umax_u(q5, t4);
      }
    }
    unsigned* op = &s_pool[sl][g * 6];
    op[0] = q0; op[1] = q1; op[2] = q2;
    op[3] = q3; op[4] = q4; op[5] = q5;
  }
  __syncthreads();

  // ---- Phase 2: fp64 exact distances for all 8*48 pool entries ----
  for (int c = tid; c < SMP * POOL; c += 256) {
    const int sl = c / POOL;
    const int p = c - sl * POOL;
    const unsigned key = s_pool[sl][p];
    const int wv = p / 12;
    const int j = wv * CPS + (int)(key & 0x1FFu);
    const float4* xp4 = (const float4*)(x + (size_t)(sbase + sl) * D_IN);
    const float4* cp4 = (const float4*)(ctrs + (size_t)j * D_IN);
    double d2a = 0.0, d2b = 0.0;
    #pragma unroll
    for (int q = 0; q < 8; ++q) {
      float4 cv = cp4[q];
      float4 xv = xp4[q];
      double df0 = (double)xv.x - (double)cv.x;
      double df1 = (double)xv.y - (double)cv.y;
      double df2 = (double)xv.z - (double)cv.z;
      double df3 = (double)xv.w - (double)cv.w;
      d2a = fma(df0, df0, d2a);
      d2b = fma(df1, df1, d2b);
      d2a = fma(df2, df2, d2a);
      d2b = fma(df3, df3, d2b);
    }
    s_pd2[sl][p] = d2a + d2b;
    s_pix[sl][p] = j;
  }
  __syncthreads();

  // ---- Phase 3: per-sample fp64 top-4, np tie-break (proven) ----
  if (tid < SMP) {
    double bd[4]; int b4[4];
    #pragma unroll
    for (int e = 0; e < 4; ++e) { bd[e] = 1e300; b4[e] = 0x7fffffff; }
    for (int m = 0; m < POOL; ++m) {
      const double d2 = s_pd2[tid][m];
      const int j = s_pix[tid][m];
      bool ins = (d2 < bd[3]) || (d2 == bd[3] && j < b4[3]);
      if (ins) {
        bd[3] = d2; b4[3] = j;
        #pragma unroll
        for (int q = 3; q > 0; --q) {
          bool sw = (bd[q] < bd[q - 1]) ||
                    (bd[q] == bd[q - 1] && b4[q] < b4[q - 1]);
          if (sw) {
            double td = bd[q]; bd[q] = bd[q - 1]; bd[q - 1] = td;
            int    tj = b4[q]; b4[q] = b4[q - 1]; b4[q - 1] = tj;
          }
        }
      }
    }
    #pragma unroll
    for (int q = 0; q < 4; ++q) s_sel[tid][q] = b4[q];
  }
  __syncthreads();   // s_cand region dead from here; reuse as diff/part

  // ---- Phase 4: diff staging (overlays dead cand region) ----
  #pragma unroll
  for (int r = 0; r < SMP * KNN * D_IN / 256; ++r) {
    int v = r * 256 + tid;
    int d = v & 31; int p = v >> 5;
    int sl = p >> 2; int j = p & 3;
    int f = s_sel[sl][j];
    s_diff[(sl * KNN + j) * (D_IN + 1) + d] =
        x[(size_t)(sbase + sl) * D_IN + d] - ctrs[(size_t)f * D_IN + d];
  }
  __syncthreads();

  // ---- Phase 5: bf16-W gather-apply (R16 uint2 form, 1 slot/thread) ----
  {
    const int slot = tid;                // 8 samples x 4 j x 8 eq = 256
    const int sl = slot >> 5;
    const int j  = (slot >> 3) & 3;
    const int eq = slot & 7;
    const int f = s_sel[sl][j];
    const uint2* wp = (const uint2*)(wb + (size_t)f * (D_IN * D_OUT));
    float4 acc = ((const float4*)(offs + (size_t)f * D_OUT))[eq];
    #pragma unroll
    for (int d = 0; d < D_IN; ++d) {
      uint2 wv = wp[d * 8 + eq];
      float w0 = __uint_as_float(wv.x << 16);
      float w1 = __uint_as_float(wv.x & 0xFFFF0000u);
      float w2 = __uint_as_float(wv.y << 16);
      float w3 = __uint_as_float(wv.y & 0xFFFF0000u);
      float xc = s_diff[(sl * KNN + j) * (D_IN + 1) + d];
      acc.x = fmaf(xc, w0, acc.x);
      acc.y = fmaf(xc, w1, acc.y);
      acc.z = fmaf(xc, w2, acc.z);
      acc.w = fmaf(xc, w3, acc.w);
    }
    s_part[(sl * KNN + j) * 8 + eq] = acc;
  }
  __syncthreads();

  {
    const int slot = tid;
    const int sl = slot >> 5;
    const int j  = (slot >> 3) & 3;
    const int eq = slot & 7;
    if (j == 0) {
      float4 a = s_part[(sl * KNN + 0) * 8 + eq];
      float4 b = s_part[(sl * KNN + 1) * 8 + eq];
      float4 c = s_part[(sl * KNN + 2) * 8 + eq];
      float4 e = s_part[(sl * KNN + 3) * 8 + eq];
      float4 o;
      o.x = (a.x + b.x) + (c.x + e.x);
      o.y = (a.y + b.y) + (c.y + e.y);
      o.z = (a.z + b.z) + (c.z + e.z);
      o.w = (a.w + b.w) + (c.w + e.w);
      ((float4*)(y + (size_t)(sbase + sl) * D_OUT))[eq] = o;
    }
  }
}

// ---------------- launch: 2 dispatches ---------------------------------------
extern "C" void kernel_launch(void* const* d_in, const int* in_sizes, int n_in,
                              void* d_out, int out_size, void* d_ws, size_t ws_size,
                              hipStream_t stream) {
  const float* x    = (const float*)d_in[0];
  const float* ctrs = (const float*)d_in[1];
  const float* wts  = (const float*)d_in[2];
  const float* offs = (const float*)d_in[3];
  float* y = (float*)d_out;

  char* ws = (char*)d_ws;
  unsigned short* xh = (unsigned short*)(ws + OFF_XH);
  unsigned short* ch = (unsigned short*)(ws + OFF_CH);
  float*          hb = (float*)(ws + OFF_HB);
  unsigned short* wb = (unsigned short*)(ws + OFF_WB);

  k_prep<<<NTOT / 256, 256, 0, stream>>>(x, ctrs, wts, xh, ch, wb, hb);
  k_mega<<<N_SMPS / SMP, 256, 0, stream>>>(xh, ch, hb, x, ctrs, wb, offs, y);
}